// Round 11
// baseline (89.282 us; speedup 1.0000x reference)
//
#include <hip/hip_runtime.h>

// PrRoIPool2D forward, MI355X. B=8, C=256, H=W=48, R=300, 7x7 bins, scale=1/16.
// R11: issue-count attack on R10.
//  - prm table padded to float4 geometry: 5 float4 prefetch loads (was 26 scalar)
//  - inv_area folded into wy in prep (PB multiply gone)
//  - shift/mask-only decomposition in P1/PA (no integer divides in hot path)
// Phases: P1 stage patch [j][i][c8] -> PA rs[pw][j][c8] -> PB combine.
// LDS 25.8 KB -> 6 blocks/CU. 9600 blocks.

#define PH 7
#define PW 7
#define NBINS 49
#define SCALE 0.0625f
#define CH 256
#define FH 48
#define FW 48
#define RNUM 300
#define CB 8                 // channels per block
#define MAXJ 23              // max patch rows
#define ROWF 28              // max patch row width (floats)
#define PRM 128              // param stride per roi (floats) -> 512 B, f4-aligned
// layout per roi (floats):
//  [ph*8+0..5]  wy[ph] (pre-scaled by inv_area)   [ph*8+6] bj bits  [+7] pad
//  [56+pw*8+0..5] wx[pw]                          [..+6]  bi bits   [+7] pad
//  [112] b bits  [113] J0 bits  [114] I0 bits  [115] (JROWS | NI4<<8) bits

__device__ __forceinline__ float hat_int(float x, float g) {
    float t = x - (g - 1.0f);
    if (t <= 0.0f) return 0.0f;
    if (t <= 1.0f) return 0.5f * t * t;
    if (t <= 2.0f) { float u = 2.0f - t; return 1.0f - 0.5f * u * u; }
    return 1.0f;
}

// ---- prep: per-roi windows/weights/bounds, once ----
__global__ __launch_bounds__(256)
void prroi_prep(const float* __restrict__ rois, float* __restrict__ prm) {
    const int r = blockIdx.x * 4 + (threadIdx.x >> 6);
    const int t = threadIdx.x & 63;
    if (r >= RNUM || t >= 15) return;

    const float* roi = rois + r * 5;
    const int   b  = (int)roi[0];
    const float x1 = roi[1] * SCALE, y1 = roi[2] * SCALE;
    const float x2 = roi[3] * SCALE, y2 = roi[4] * SCALE;
    const float roi_w = fmaxf(x2 - x1, 0.0f), roi_h = fmaxf(y2 - y1, 0.0f);
    const float bin_w = roi_w / (float)PW, bin_h = roi_h / (float)PH;
    const float area = bin_w * bin_h;
    const float inv_area = (area > 0.0f) ? (1.0f / area) : 0.0f;

    const float ylo = fminf(y1, y2), yhi = fmaxf(y1, y2);
    const float xlo = fminf(x1, x2), xhi = fmaxf(x1, x2);
    const int j1 = min(FH - 1, (int)floorf(yhi) + 1);
    const int i1 = min(FW - 1, (int)floorf(xhi) + 1);
    const int J0 = min(max(0, (int)floorf(ylo) - 1), FH - 6);
    const int I0 = min(max(0, (int)floorf(xlo) - 1) & ~3, FW - 8);
    const int JROWS = min(FH - J0, max(j1 - J0 + 1, 6));        // 6..23
    int NI4 = min(((i1 - I0) >> 2) + 1, (FW - I0) >> 2);
    NI4 = max(NI4, 2);                                           // 2..7

    float* p = prm + (size_t)r * PRM;
    if (t < PH) {
        const int ph = t;
        const float ya = y1 + ph * bin_h, yb = ya + bin_h;
        const int base = min(max((int)floorf(ya) - 1, J0), J0 + JROWS - 6);
#pragma unroll
        for (int k = 0; k < 6; ++k) {
            const float g = (float)(base + k);
            // inv_area folded in: PB needs no multiply
            p[ph * 8 + k] = (hat_int(yb, g) - hat_int(ya, g)) * inv_area;
        }
        p[ph * 8 + 6] = __int_as_float(base - J0);
        p[ph * 8 + 7] = 0.0f;
    } else if (t < PH + PW) {
        const int pw = t - PH;
        const float xa = x1 + pw * bin_w, xb = xa + bin_w;
        const int base = min(max((int)floorf(xa) - 1, I0), I0 + 4 * NI4 - 6);
#pragma unroll
        for (int k = 0; k < 6; ++k) {
            const float g = (float)(base + k);
            p[56 + pw * 8 + k] = hat_int(xb, g) - hat_int(xa, g);
        }
        p[56 + pw * 8 + 6] = __int_as_float(base - I0);
        p[56 + pw * 8 + 7] = 0.0f;
    } else {                                                     // t == 14
        p[112] = __int_as_float(b);
        p[113] = __int_as_float(J0);
        p[114] = __int_as_float(I0);
        p[115] = __int_as_float(JROWS | (NI4 << 8));
    }
}

// ---- main ----
__global__ __launch_bounds__(256)
void prroi_main(const float* __restrict__ feat,
                const float* __restrict__ prm,
                float* __restrict__ out) {
    const int cblk = blockIdx.x;        // 0..31
    const int r    = blockIdx.y;        // 0..299
    const int c0   = cblk * CB;
    const int tid  = threadIdx.x;

    __shared__ float patch[MAXJ * ROWF * CB];   // [j][i][c8] 20608 B
    __shared__ float rs[PW * MAXJ * CB];        // [pw][j][c8]  5152 B

    const float* p = prm + (size_t)r * PRM;

    // ---- prefetch: 5 float4 loads total ----
    const float4 misc = *(const float4*)(p + 112);
    // PA params: thread owns (qA, pwA), j sweeps tid>>4 step 16
    const int qA  = tid & 1;
    const int pwA = (tid >> 1) & 7;             // 7 -> idle lane
    const int jA  = tid >> 4;                   // 0..15
    const float4 wxv0 = *(const float4*)(p + 56 + pwA * 8);
    const float4 wxv1 = *(const float4*)(p + 56 + pwA * 8 + 4);
    // PB params
    const int bin = tid & 63;
    const int cp  = tid >> 6;
    const int phv = bin / 7;                    // magic-mul, once
    const int pwv = bin - phv * 7;
    const float4 wyv0 = *(const float4*)(p + phv * 8);
    const float4 wyv1 = *(const float4*)(p + phv * 8 + 4);

    const int b      = __float_as_int(misc.x);
    const int J0     = __float_as_int(misc.y);
    const int I0     = __float_as_int(misc.z);
    const int packed = __float_as_int(misc.w);
    const int JROWS  = packed & 255;
    const int NI4    = packed >> 8;
    const int biA    = __float_as_int(wxv1.z);
    const int bj     = __float_as_int(wyv1.z);

    // ---- P1: stage patch, shift/mask decomposition, pointer-increment loop ----
    const int i4P = tid & 7;                    // 0..7 (idle if >= NI4)
    const int qP  = (tid >> 3) & 1;
    const int jbP = tid >> 4;                   // 0..15
    if (i4P < NI4) {
        const float* src = feat + (size_t)(b * CH + c0 + 4 * qP) * FH * FW
                         + (size_t)(J0 + jbP) * FW + I0 + 4 * i4P;
        float* dst = &patch[((size_t)jbP * ROWF + 4 * i4P) * CB + 4 * qP];
        for (int j = jbP; j < JROWS; j += 16) {
            const float4 v0 = *(const float4*)(src);
            const float4 v1 = *(const float4*)(src + FH * FW);
            const float4 v2 = *(const float4*)(src + 2 * FH * FW);
            const float4 v3 = *(const float4*)(src + 3 * FH * FW);
            *(float4*)(dst + 0 * CB) = make_float4(v0.x, v1.x, v2.x, v3.x);
            *(float4*)(dst + 1 * CB) = make_float4(v0.y, v1.y, v2.y, v3.y);
            *(float4*)(dst + 2 * CB) = make_float4(v0.z, v1.z, v2.z, v3.z);
            *(float4*)(dst + 3 * CB) = make_float4(v0.w, v1.w, v2.w, v3.w);
            src += 16 * FW;
            dst += 16 * ROWF * CB;
        }
    }
    __syncthreads();

    // ---- PA: rs[pw][j][c8] = sum_i wx * patch (weights in regs) ----
    if (pwA < PW) {
        const float* base0 = &patch[((size_t)jA * ROWF + biA) * CB + 4 * qA];
        float* rdst = &rs[((size_t)pwA * MAXJ + jA) * CB + 4 * qA];
        for (int j = jA; j < JROWS; j += 16) {
            float ax, ay, az, aw;
            {
                const float4 v = *(const float4*)(base0 + 0 * CB);
                ax = wxv0.x * v.x; ay = wxv0.x * v.y; az = wxv0.x * v.z; aw = wxv0.x * v.w;
            }
            {
                const float4 v = *(const float4*)(base0 + 1 * CB);
                ax += wxv0.y * v.x; ay += wxv0.y * v.y; az += wxv0.y * v.z; aw += wxv0.y * v.w;
            }
            {
                const float4 v = *(const float4*)(base0 + 2 * CB);
                ax += wxv0.z * v.x; ay += wxv0.z * v.y; az += wxv0.z * v.z; aw += wxv0.z * v.w;
            }
            {
                const float4 v = *(const float4*)(base0 + 3 * CB);
                ax += wxv0.w * v.x; ay += wxv0.w * v.y; az += wxv0.w * v.z; aw += wxv0.w * v.w;
            }
            {
                const float4 v = *(const float4*)(base0 + 4 * CB);
                ax += wxv1.x * v.x; ay += wxv1.x * v.y; az += wxv1.x * v.z; aw += wxv1.x * v.w;
            }
            {
                const float4 v = *(const float4*)(base0 + 5 * CB);
                ax += wxv1.y * v.x; ay += wxv1.y * v.y; az += wxv1.y * v.z; aw += wxv1.y * v.w;
            }
            *(float4*)rdst = make_float4(ax, ay, az, aw);
            base0 += 16 * ROWF * CB;
            rdst  += 16 * CB;
        }
    }
    __syncthreads();

    // ---- PB: combine over rows (wy pre-scaled by inv_area) ----
    if (bin < NBINS) {
        const float* rbase = &rs[((size_t)pwv * MAXJ + bj) * CB + 2 * cp];
        float ax = 0.0f, ay = 0.0f;
        {
            const float2 v = *(const float2*)(rbase + 0 * CB);
            ax += wyv0.x * v.x; ay += wyv0.x * v.y;
        }
        {
            const float2 v = *(const float2*)(rbase + 1 * CB);
            ax += wyv0.y * v.x; ay += wyv0.y * v.y;
        }
        {
            const float2 v = *(const float2*)(rbase + 2 * CB);
            ax += wyv0.z * v.x; ay += wyv0.z * v.y;
        }
        {
            const float2 v = *(const float2*)(rbase + 3 * CB);
            ax += wyv0.w * v.x; ay += wyv0.w * v.y;
        }
        {
            const float2 v = *(const float2*)(rbase + 4 * CB);
            ax += wyv1.x * v.x; ay += wyv1.x * v.y;
        }
        {
            const float2 v = *(const float2*)(rbase + 5 * CB);
            ax += wyv1.y * v.x; ay += wyv1.y * v.y;
        }
        float* o = out + ((size_t)r * CH + c0 + 2 * cp) * NBINS + bin;
        o[0]     = ax;
        o[NBINS] = ay;
    }
}

extern "C" void kernel_launch(void* const* d_in, const int* in_sizes, int n_in,
                              void* d_out, int out_size, void* d_ws, size_t ws_size,
                              hipStream_t stream) {
    const float* feat = (const float*)d_in[0];
    const float* rois = (const float*)d_in[1];
    float* out = (float*)d_out;
    float* prm = (float*)d_ws;   // 300 * 128 * 4 = 153.6 KB

    prroi_prep<<<(RNUM + 3) / 4, 256, 0, stream>>>(rois, prm);
    prroi_main<<<dim3(CH / CB, RNUM), 256, 0, stream>>>(feat, prm, out);
}